// Round 19
// baseline (291.134 us; speedup 1.0000x reference)
//
#include <hip/hip_runtime.h>

#define N_NODES 50000
#define E_EDGES 800000
#define EP (E_EDGES + N_NODES)   // edges + self loops = 850000
#define IN_CH 128
#define HID 64
#define HEADS 3
#define HC 192
#define OUT_CH 32
#define SLOPE 0.2f

#define N4 12500                 // N_NODES / 4 (exact)
#define SCAN_BLK 49              // ceil(N4 / 256)
#define NBKT 391                 // ceil(N_NODES / 128) dst buckets
#define SCAP 4096                // pass-2 LDS capacity (mean 2176, +41 sigma)
#define EPB 8192                 // edges per scatter1 block
#define NB1 104                  // ceil(EP / EPB)

// mega_pre job boundaries
#define MB_W1 96                 // 128k x 192n: 4 k-tiles x 24 n-tiles
#define MB_W2 (MB_W1 + 144)      // 192k x 192n: 6 k-tiles x 24 n-tiles
#define MB_FOLD (MB_W2 + 25)
#define MB_HIST (MB_FOLD + 3321) // ceil(EP/256)

typedef __attribute__((ext_vector_type(8))) short bf16x8;
typedef __attribute__((ext_vector_type(4))) float f32x4;

__device__ __forceinline__ unsigned short f2bf(float f) {
    unsigned int u = __float_as_uint(f);
    u = (u + 0x7fffu + ((u >> 16) & 1u)) >> 16;   // round-to-nearest-even
    return (unsigned short)u;
}
__device__ __forceinline__ float loF(unsigned int u) { return __uint_as_float(u << 16); }
__device__ __forceinline__ float hiF(unsigned int u) { return __uint_as_float(u & 0xFFFF0000u); }

// monotone float<->uint key (memset-0 init acts as -inf)
__device__ __forceinline__ unsigned int fkey(float f) {
    unsigned int u = __float_as_uint(f);
    return (u & 0x80000000u) ? ~u : (u | 0x80000000u);
}
__device__ __forceinline__ float unfkey(unsigned int k) {
    unsigned int u = (k & 0x80000000u) ? (k ^ 0x80000000u) : ~k;
    return __uint_as_float(u);
}

// ---------------- fused preprocessing: wconv1 | wconv2 | fold | hist ----------------

__global__ __launch_bounds__(256) void mega_pre_kernel(
    const float* __restrict__ W1, unsigned short* __restrict__ W1T,
    const float* __restrict__ W2, unsigned short* __restrict__ W2T,
    const float* __restrict__ Wf1, const float* __restrict__ bf1,
    const float* __restrict__ Wf2, const float* __restrict__ bf2,
    unsigned short* __restrict__ WfTb, float* __restrict__ bf,
    const int* __restrict__ ei, int* __restrict__ cnt) {
    int b = blockIdx.x, t = threadIdx.x;
    if (b < MB_W1) {                          // W1 [128][192] -> W1T [192][128] bf16
        int k = (b & 3) * 32 + (t & 31);
        int n = (b >> 2) * 8 + (t >> 5);
        W1T[n * IN_CH + k] = f2bf(W1[(size_t)k * HC + n]);
    } else if (b < MB_W2) {                   // W2 [192][192] -> W2T [192][192] bf16
        int bb = b - MB_W1;
        int k = (bb % 6) * 32 + (t & 31);
        int n = (bb / 6) * 8 + (t >> 5);
        W2T[n * HC + k] = f2bf(W2[(size_t)k * HC + n]);
    } else if (b < MB_FOLD) {                 // WfT = (Wf1@Wf2)^T bf16, bf = bf1@Wf2 + bf2
        int id = (b - MB_W2) * 256 + t;
        if (id < HC * OUT_CH) {
            int i = id / OUT_CH, j = id % OUT_CH;
            float s = 0.f;
            for (int k = 0; k < 64; ++k) s += Wf1[i * 64 + k] * Wf2[k * OUT_CH + j];
            WfTb[j * HC + i] = f2bf(s);
        } else if (id < HC * OUT_CH + OUT_CH) {
            int j = id - HC * OUT_CH;
            float s = bf2[j];
            for (int k = 0; k < 64; ++k) s += bf1[k] * Wf2[k * OUT_CH + j];
            bf[j] = s;
        }
    } else {                                  // degree histogram
        int i = (b - MB_FOLD) * 256 + t;
        if (i < EP) {
            int d = (i < E_EDGES) ? ei[E_EDGES + i] : (i - E_EDGES);
            atomicAdd(&cnt[d], 1);
        }
    }
}

// ---- hierarchical exclusive scan ----

__global__ __launch_bounds__(256) void scan_local_kernel(int* __restrict__ cnt,
                                                         int* __restrict__ offs,
                                                         int* __restrict__ bsum) {
    __shared__ int s[256];
    int t = threadIdx.x;
    int g = blockIdx.x * 256 + t;          // int4 index
    int4 v = make_int4(0, 0, 0, 0);
    if (g < N4) v = ((const int4*)cnt)[g];
    int sum = v.x + v.y + v.z + v.w;
    s[t] = sum; __syncthreads();
    #pragma unroll
    for (int o = 1; o < 256; o <<= 1) {
        int u = (t >= o) ? s[t - o] : 0;
        __syncthreads();
        s[t] += u;
        __syncthreads();
    }
    int ex = s[t] - sum;
    if (g < N4) {
        int4 w;
        w.x = ex;
        w.y = ex + v.x;
        w.z = ex + v.x + v.y;
        w.w = ex + v.x + v.y + v.z;
        ((int4*)offs)[g] = w;
    }
    if (t == 255) bsum[blockIdx.x] = s[255];
}

__global__ __launch_bounds__(256) void scan_add_kernel(int* __restrict__ offs,
                                                       const int* __restrict__ bsum) {
    int lane = threadIdx.x & 63;
    int orig = (lane < SCAN_BLK) ? bsum[lane] : 0;
    int v = orig;
    #pragma unroll
    for (int o = 1; o < 64; o <<= 1) {
        int u = __shfl_up(v, o);
        if (lane >= o) v += u;
    }
    // all lanes active for every shuffle (ds_bpermute from an inactive lane is UB)
    int add = __shfl(v, blockIdx.x) - __shfl(orig, blockIdx.x);   // exclusive prefix
    int total = __shfl(v, SCAN_BLK - 1);
    int g = blockIdx.x * 256 + threadIdx.x;
    if (g < N4) {
        int4 w = ((int4*)offs)[g];
        w.x += add; w.y += add; w.z += add; w.w += add;
        ((int4*)offs)[g] = w;
    }
    if (blockIdx.x == 0 && threadIdx.x == 0) offs[N_NODES] = total;
}

// ---- two-pass bucket sort with block-aggregated reservation ----

__global__ __launch_bounds__(256) void scatter1_kernel(const int* __restrict__ ei,
                                                       const int* __restrict__ offs,
                                                       int* __restrict__ bcnt,
                                                       unsigned int* __restrict__ stage) {
    __shared__ unsigned int pack[EPB];        // [bucket:9][lslot:13][dloc:7]
    __shared__ int hist[NBKT];
    __shared__ int basec[NBKT];
    int t = threadIdx.x;
    int e0 = blockIdx.x * EPB;
    int e1 = e0 + EPB; if (e1 > EP) e1 = EP;
    int n = e1 - e0;
    for (int b = t; b < NBKT; b += 256) hist[b] = 0;
    __syncthreads();
    for (int i = t; i < n; i += 256) {
        int gi = e0 + i;
        int d_ = (gi < E_EDGES) ? ei[E_EDGES + gi] : (gi - E_EDGES);
        int b = d_ >> 7;
        int lslot = atomicAdd(&hist[b], 1);
        pack[i] = ((unsigned int)b << 20) | ((unsigned int)lslot << 7) | (unsigned int)(d_ & 127);
    }
    __syncthreads();
    for (int b = t; b < NBKT; b += 256) {
        int h = hist[b];
        int res = (h > 0) ? atomicAdd(&bcnt[b], h) : 0;
        basec[b] = offs[b << 7] + res;
    }
    __syncthreads();
    for (int i = t; i < n; i += 256) {
        int gi = e0 + i;
        int s_ = (gi < E_EDGES) ? ei[gi] : (gi - E_EDGES);
        unsigned int pk = pack[i];
        int b = pk >> 20;
        int lslot = (pk >> 7) & 0x1FFF;
        unsigned int dloc = pk & 127u;
        stage[basec[b] + lslot] = (dloc << 16) | (unsigned int)s_;
    }
}

// Pass 2: per-bucket LDS counting sort; coalesced output.
__global__ __launch_bounds__(256) void scatter2_kernel(const unsigned int* __restrict__ stage,
                                                       const int* __restrict__ offs,
                                                       int* __restrict__ src_sort) {
    __shared__ unsigned int ents[SCAP];
    __shared__ int outb[SCAP];
    __shared__ int lcnt[128];
    __shared__ int lsc[128];
    int b = blockIdx.x, t = threadIdx.x;
    int beg = offs[b << 7];
    int hi = (b << 7) + 128; if (hi > N_NODES) hi = N_NODES;
    int end = offs[hi];
    int n = end - beg;
    if (t < 128) lcnt[t] = 0;
    __syncthreads();
    for (int i = t; i < n; i += 256) {
        unsigned int v = stage[beg + i];
        int dloc = (v >> 16) & 127;
        int slot = atomicAdd(&lcnt[dloc], 1);
        ents[i] = v | ((unsigned int)slot << 23);
    }
    __syncthreads();
    int cv = (t < 128) ? lcnt[t] : 0;
    if (t < 128) lsc[t] = cv;
    __syncthreads();
    #pragma unroll
    for (int o = 1; o < 128; o <<= 1) {
        int u = 0;
        if (t < 128 && t >= o) u = lsc[t - o];
        __syncthreads();
        if (t < 128) lsc[t] += u;
        __syncthreads();
    }
    if (t < 128) lsc[t] -= cv;                 // exclusive prefix
    __syncthreads();
    for (int i = t; i < n; i += 256) {
        unsigned int v = ents[i];
        int dloc = (v >> 16) & 127;
        int slot = v >> 23;
        outb[lsc[dloc] + slot] = (int)(v & 0xFFFFu);
    }
    __syncthreads();
    for (int i = t; i < n; i += 256) src_sort[beg + i] = outb[i];
}

// ---------------- MFMA GEMM: [M x K] @ [K x 192]bf16 -> Hb bf16 + alphas + global AS max ----------------

#define GBM 128
#define GBK 64
#define LDA 72        // row pad: 144 B, 16B-aligned, even bank spread
#define CS_STR 200    // epilogue C row stride (elems)

template <int K, bool XF32>
__global__ __launch_bounds__(256) void gemm_mfma_kernel(
    const float* __restrict__ Af, const unsigned short* __restrict__ Ab,
    const unsigned short* __restrict__ Wt,
    const float* __restrict__ a_src, const float* __restrict__ a_dst,
    unsigned short* __restrict__ Hb, float* __restrict__ AS, float* __restrict__ AD,
    unsigned int* __restrict__ mk) {
    __shared__ __align__(16) unsigned char smem[51200];
    __shared__ float pmx[4][3];
    unsigned short (*As)[LDA] = (unsigned short (*)[LDA])smem;
    unsigned short (*Bs)[LDA] = (unsigned short (*)[LDA])(smem + GBM * LDA * 2);
    int tid = threadIdx.x;
    int wid = tid >> 6, lane = tid & 63;
    int l15 = lane & 15, l4 = lane >> 4;
    int m0 = blockIdx.x * GBM;
    int sr = tid >> 3, sc = (tid & 7) * 8;

    f32x4 acc[2][12];
    #pragma unroll
    for (int m = 0; m < 2; ++m)
        #pragma unroll
        for (int n = 0; n < 12; ++n) acc[m][n] = (f32x4){0.f, 0.f, 0.f, 0.f};

    for (int kb = 0; kb < K; kb += GBK) {
        #pragma unroll
        for (int i = 0; i < 4; ++i) {           // A tile: 128 rows x 64 k
            int r = sr + 32 * i, grow = m0 + r;
            uint4 v = make_uint4(0, 0, 0, 0);
            if (XF32) {
                if (grow < N_NODES) {
                    const float* xp = Af + (size_t)grow * K + kb + sc;
                    float4 v0 = *(const float4*)xp;
                    float4 v1 = *(const float4*)(xp + 4);
                    v.x = (unsigned int)f2bf(v0.x) | ((unsigned int)f2bf(v0.y) << 16);
                    v.y = (unsigned int)f2bf(v0.z) | ((unsigned int)f2bf(v0.w) << 16);
                    v.z = (unsigned int)f2bf(v1.x) | ((unsigned int)f2bf(v1.y) << 16);
                    v.w = (unsigned int)f2bf(v1.z) | ((unsigned int)f2bf(v1.w) << 16);
                }
            } else {
                if (grow < N_NODES) v = *(const uint4*)&Ab[(size_t)grow * K + kb + sc];
            }
            *(uint4*)&As[r][sc] = v;
        }
        #pragma unroll
        for (int i = 0; i < 6; ++i) {           // B tile: 192 n x 64 k (k-contig)
            int n = sr + 32 * i;
            uint4 v = *(const uint4*)&Wt[(size_t)n * K + kb + sc];
            *(uint4*)&Bs[n][sc] = v;
        }
        __syncthreads();
        #pragma unroll
        for (int ks = 0; ks < 2; ++ks) {
            int ko = ks * 32 + l4 * 8;
            bf16x8 a0 = *(const bf16x8*)&As[wid * 32 + l15][ko];
            bf16x8 a1 = *(const bf16x8*)&As[wid * 32 + 16 + l15][ko];
            #pragma unroll
            for (int n = 0; n < 12; ++n) {
                bf16x8 b = *(const bf16x8*)&Bs[n * 16 + l15][ko];
                acc[0][n] = __builtin_amdgcn_mfma_f32_16x16x32_bf16(a0, b, acc[0][n], 0, 0, 0);
                acc[1][n] = __builtin_amdgcn_mfma_f32_16x16x32_bf16(a1, b, acc[1][n], 0, 0, 0);
            }
        }
        __syncthreads();
    }

    // ---- fused alpha + per-wave AS max ----
    float asv[12], adv[12];
    #pragma unroll
    for (int n = 0; n < 12; ++n) {
        asv[n] = a_src[n * 16 + l15];
        adv[n] = a_dst[n * 16 + l15];
    }
    float pm[3] = {-1e30f, -1e30f, -1e30f};
    #pragma unroll
    for (int m = 0; m < 2; ++m)
        #pragma unroll
        for (int r = 0; r < 4; ++r) {
            float ps[3], pd[3];
            #pragma unroll
            for (int h = 0; h < 3; ++h) {
                float s = 0.f, d = 0.f;
                #pragma unroll
                for (int j = 0; j < 4; ++j) {
                    float v = acc[m][4 * h + j][r];
                    s += v * asv[4 * h + j];
                    d += v * adv[4 * h + j];
                }
                #pragma unroll
                for (int o = 1; o < 16; o <<= 1) { s += __shfl_xor(s, o); d += __shfl_xor(d, o); }
                ps[h] = s; pd[h] = d;
                pm[h] = fmaxf(pm[h], s);
            }
            if (l15 == 0) {
                int grow = m0 + wid * 32 + m * 16 + l4 * 4 + r;
                if (grow < N_NODES) {
                    #pragma unroll
                    for (int h = 0; h < 3; ++h) {
                        AS[grow * 3 + h] = ps[h];
                        AD[grow * 3 + h] = pd[h];
                    }
                }
            }
        }
    // wave-level max (all lanes active for shuffles), then stage to LDS
    #pragma unroll
    for (int h = 0; h < 3; ++h) {
        pm[h] = fmaxf(pm[h], __shfl_xor(pm[h], 16));
        pm[h] = fmaxf(pm[h], __shfl_xor(pm[h], 32));
    }
    if (lane == 0) { pmx[wid][0] = pm[0]; pmx[wid][1] = pm[1]; pmx[wid][2] = pm[2]; }

    // ---- Hb store via per-wave LDS transpose (reuse tile space) ----
    unsigned short* Cw = (unsigned short*)smem + wid * 32 * CS_STR;
    #pragma unroll
    for (int m = 0; m < 2; ++m)
        #pragma unroll
        for (int n = 0; n < 12; ++n)
            #pragma unroll
            for (int r = 0; r < 4; ++r)
                Cw[(m * 16 + l4 * 4 + r) * CS_STR + n * 16 + l15] = f2bf(acc[m][n][r]);
    __syncthreads();
    #pragma unroll
    for (int i = 0; i < 12; ++i) {
        int c = lane + 64 * i;                 // 768 chunks of 16B per wave
        int row = c / 24, off = c % 24;
        int grow = m0 + wid * 32 + row;
        if (grow < N_NODES) {
            uint4 v = *(const uint4*)&Cw[row * CS_STR + off * 8];
            *(uint4*)&Hb[(size_t)grow * HC + off * 8] = v;
        }
    }
    // one atomicMax per block per head (contention: 391 blocks x 3 addrs - negligible)
    if (tid < 3) {
        float bm = fmaxf(fmaxf(pmx[0][tid], pmx[1][tid]), fmaxf(pmx[2][tid], pmx[3][tid]));
        atomicMax(&mk[tid], fkey(bm));
    }
}

// ---------------- single-pass softmax + gather-sum: TWO waves per dst ----------------
// Block = 4 waves = 2 dsts x 2 cooperating waves. Wave k handles edge-blocks
// beg+4k, beg+4k+8, ... (stride 8): half the serial depth of R12, no duplicated
// work (global-max shift needs no segment pass). Partials combined via LDS.
// Within-wave layout = R12: 4 slots x 16 lanes, lane owns 12 channels (3x uint2).

__global__ __launch_bounds__(256) void aggregate_kernel(
    const int* __restrict__ src_sort, const int* __restrict__ offs,
    const float* __restrict__ AS, const float* __restrict__ AD,
    const unsigned int* __restrict__ mkey,
    const unsigned short* __restrict__ Hb, const float* __restrict__ bias,
    unsigned short* __restrict__ Aout) {
    __shared__ float comb[2][16][14];          // [dst-half][lane][A0..C3,den] (+pad)
    int tid = threadIdx.x;
    int did = tid >> 7;                        // dst half (0..1)
    int k = (tid >> 6) & 1;                    // wave-in-pair
    int w = blockIdx.x * 2 + did;
    int lane = tid & 63;
    int g = lane >> 4, l = lane & 15;
    int beg = offs[w], end = offs[w + 1];

    float ad = 0.f, m = 0.f;
    if (l < 3) {
        ad = AD[w * 3 + l];
        float sm = unfkey(mkey[l]) + ad;
        m = fmaxf(sm, SLOPE * sm);             // lrelu(gmax+ad) >= max_e lrelu(AS+ad)
    }

    int c0 = l * 12;
    int h0 = c0 >> 6, h1 = (c0 + 4) >> 6, h2 = (c0 + 8) >> 6;
    float A0 = 0.f, A1 = 0.f, A2 = 0.f, A3 = 0.f;
    float B0 = 0.f, B1 = 0.f, B2 = 0.f, B3 = 0.f;
    float C0 = 0.f, C1 = 0.f, C2 = 0.f, C3 = 0.f;
    float den = 0.f;

    // prologue (wave k starts at beg + 4k)
    int pstart = beg + 4 * k;
    int p = pstart + g;
    bool pv = p < end;
    int s_ = src_sort[pv ? p : (end - 1)];     // deg >= 1 (self-loop)
    float e_;
    {
        float v = (l < 3) ? (AS[s_ * 3 + l] + ad) : 0.f;
        v = fmaxf(v, SLOPE * v);
        e_ = (pv && l < 3) ? __expf(v - m) : 0.f;
    }
    for (int p0 = pstart; p0 < end; p0 += 8) {
        // next iteration's index load first
        int pn = p0 + 8 + g;
        bool pnv = pn < end;
        int sn = src_sort[pnv ? pn : (end - 1)];
        // current row gathers (latency hidden under next-score computation)
        const unsigned short* hr = Hb + (unsigned)s_ * HC + c0;
        uint2 v0 = *(const uint2*)hr;
        uint2 v1 = *(const uint2*)(hr + 4);
        uint2 v2 = *(const uint2*)(hr + 8);
        // next iteration's score (independent of gathers)
        float en;
        {
            float v = (l < 3) ? (AS[sn * 3 + l] + ad) : 0.f;
            v = fmaxf(v, SLOPE * v);
            en = (pnv && l < 3) ? __expf(v - m) : 0.f;
        }
        bool cv = (p0 + g) < end;
        float ec = cv ? e_ : 0.f;
        den += ec;
        float w0 = __shfl(ec, g * 16 + h0);
        float w1 = __shfl(ec, g * 16 + h1);
        float w2 = __shfl(ec, g * 16 + h2);
        A0 += w0 * loF(v0.x); A1 += w0 * hiF(v0.x); A2 += w0 * loF(v0.y); A3 += w0 * hiF(v0.y);
        B0 += w1 * loF(v1.x); B1 += w1 * hiF(v1.x); B2 += w1 * loF(v1.y); B3 += w1 * hiF(v1.y);
        C0 += w2 * loF(v2.x); C1 += w2 * hiF(v2.x); C2 += w2 * loF(v2.y); C3 += w2 * hiF(v2.y);
        s_ = sn; e_ = en;
    }

    // within-wave cross-slot reduction
    #pragma unroll
    for (int o = 16; o < 64; o <<= 1) {
        A0 += __shfl_xor(A0, o); A1 += __shfl_xor(A1, o); A2 += __shfl_xor(A2, o); A3 += __shfl_xor(A3, o);
        B0 += __shfl_xor(B0, o); B1 += __shfl_xor(B1, o); B2 += __shfl_xor(B2, o); B3 += __shfl_xor(B3, o);
        C0 += __shfl_xor(C0, o); C1 += __shfl_xor(C1, o); C2 += __shfl_xor(C2, o); C3 += __shfl_xor(C3, o);
        den += __shfl_xor(den, o);
    }

    // cross-wave combine via LDS: wave 1 stores, wave 0 finishes
    if (k == 1 && lane < 16) {
        float* cp = comb[did][lane];
        cp[0] = A0; cp[1] = A1; cp[2] = A2; cp[3] = A3;
        cp[4] = B0; cp[5] = B1; cp[6] = B2; cp[7] = B3;
        cp[8] = C0; cp[9] = C1; cp[10] = C2; cp[11] = C3;
        cp[12] = den;
    }
    __syncthreads();
    if (k == 0) {
        if (lane < 16) {
            const float* cp = comb[did][lane];
            A0 += cp[0]; A1 += cp[1]; A2 += cp[2]; A3 += cp[3];
            B0 += cp[4]; B1 += cp[5]; B2 += cp[6]; B3 += cp[7];
            C0 += cp[8]; C1 += cp[9]; C2 += cp[10]; C3 += cp[11];
            den += cp[12];
        }
        // all 64 lanes participate in shuffles (den garbage in lanes>=16 unused)
        float i0 = 1.f / (__shfl(den, h0) + 1e-16f);
        float i1 = 1.f / (__shfl(den, h1) + 1e-16f);
        float i2 = 1.f / (__shfl(den, h2) + 1e-16f);
        if (lane < 16) {
            float4 bi0 = *(const float4*)&bias[c0];
            float4 bi1 = *(const float4*)&bias[c0 + 4];
            float4 bi2 = *(const float4*)&bias[c0 + 8];
            A0 = A0 * i0 + bi0.x; A1 = A1 * i0 + bi0.y; A2 = A2 * i0 + bi0.z; A3 = A3 * i0 + bi0.w;
            B0 = B0 * i1 + bi1.x; B1 = B1 * i1 + bi1.y; B2 = B2 * i1 + bi1.z; B3 = B3 * i1 + bi1.w;
            C0 = C0 * i2 + bi2.x; C1 = C1 * i2 + bi2.y; C2 = C2 * i2 + bi2.z; C3 = C3 * i2 + bi2.w;
            A0 = (A0 > 0.f) ? A0 : (__expf(A0) - 1.f);
            A1 = (A1 > 0.f) ? A1 : (__expf(A1) - 1.f);
            A2 = (A2 > 0.f) ? A2 : (__expf(A2) - 1.f);
            A3 = (A3 > 0.f) ? A3 : (__expf(A3) - 1.f);
            B0 = (B0 > 0.f) ? B0 : (__expf(B0) - 1.f);
            B1 = (B1 > 0.f) ? B1 : (__expf(B1) - 1.f);
            B2 = (B2 > 0.f) ? B2 : (__expf(B2) - 1.f);
            B3 = (B3 > 0.f) ? B3 : (__expf(B3) - 1.f);
            C0 = (C0 > 0.f) ? C0 : (__expf(C0) - 1.f);
            C1 = (C1 > 0.f) ? C1 : (__expf(C1) - 1.f);
            C2 = (C2 > 0.f) ? C2 : (__expf(C2) - 1.f);
            C3 = (C3 > 0.f) ? C3 : (__expf(C3) - 1.f);
            unsigned short* op = Aout + (size_t)w * HC + c0;
            uint2 o0, o1, o2;
            o0.x = (unsigned int)f2bf(A0) | ((unsigned int)f2bf(A1) << 16);
            o0.y = (unsigned int)f2bf(A2) | ((unsigned int)f2bf(A3) << 16);
            o1.x = (unsigned int)f2bf(B0) | ((unsigned int)f2bf(B1) << 16);
            o1.y = (unsigned int)f2bf(B2) | ((unsigned int)f2bf(B3) << 16);
            o2.x = (unsigned int)f2bf(C0) | ((unsigned int)f2bf(C1) << 16);
            o2.y = (unsigned int)f2bf(C2) | ((unsigned int)f2bf(C3) << 16);
            *(uint2*)op = o0;
            *(uint2*)(op + 4) = o1;
            *(uint2*)(op + 8) = o2;
        }
    }
}

// ---------------- MFMA MLP head: out = act(bf16) @ WfT^T + bf ----------------

__global__ __launch_bounds__(256) void mlp_mfma_kernel(
    const unsigned short* __restrict__ act, const unsigned short* __restrict__ WfTb,
    const float* __restrict__ bf, float* __restrict__ out) {
    int tid = threadIdx.x;
    int wid = tid >> 6, lane = tid & 63;
    int l15 = lane & 15, l4 = lane >> 4;
    int m0 = blockIdx.x * 128 + wid * 32;

    f32x4 acc[2][2];
    #pragma unroll
    for (int m = 0; m < 2; ++m)
        #pragma unroll
        for (int n = 0; n < 2; ++n) acc[m][n] = (f32x4){0.f, 0.f, 0.f, 0.f};

    int r0 = m0 + l15, r1 = m0 + 16 + l15;
    bool v0r = r0 < N_NODES, v1r = r1 < N_NODES;
    const unsigned short* a0p = act + (size_t)(v0r ? r0 : 0) * HC;
    const unsigned short* a1p = act + (size_t)(v1r ? r1 : 0) * HC;
    const unsigned short* b0p = WfTb + (size_t)l15 * HC;
    const unsigned short* b1p = WfTb + (size_t)(16 + l15) * HC;

    #pragma unroll
    for (int ks = 0; ks < 6; ++ks) {
        int k0 = ks * 32 + l4 * 8;
        bf16x8 a0 = *(const bf16x8*)&a0p[k0];
        bf16x8 a1 = *(const bf16x8*)&a1p[k0];
        bf16x8 b0 = *(const bf16x8*)&b0p[k0];
        bf16x8 b1 = *(const bf16x8*)&b1p[k0];
        acc[0][0] = __builtin_amdgcn_mfma_f32_16x16x32_bf16(a0, b0, acc[0][0], 0, 0, 0);
        acc[0][1] = __builtin_amdgcn_mfma_f32_16x16x32_bf16(a0, b1, acc[0][1], 0, 0, 0);
        acc[1][0] = __builtin_amdgcn_mfma_f32_16x16x32_bf16(a1, b0, acc[1][0], 0, 0, 0);
        acc[1][1] = __builtin_amdgcn_mfma_f32_16x16x32_bf16(a1, b1, acc[1][1], 0, 0, 0);
    }

    float bv0 = bf[l15], bv1 = bf[16 + l15];
    #pragma unroll
    for (int m = 0; m < 2; ++m)
        #pragma unroll
        for (int r = 0; r < 4; ++r) {
            int row = m0 + m * 16 + l4 * 4 + r;
            if (row < N_NODES) {
                out[(size_t)row * OUT_CH + l15]      = acc[m][0][r] + bv0;
                out[(size_t)row * OUT_CH + 16 + l15] = acc[m][1][r] + bv1;
            }
        }
}

// ---------------- launch ----------------

extern "C" void kernel_launch(void* const* d_in, const int* in_sizes, int n_in,
                              void* d_out, int out_size, void* d_ws, size_t ws_size,
                              hipStream_t stream) {
    (void)in_sizes; (void)n_in; (void)out_size; (void)ws_size;
    const float* x   = (const float*)d_in[0];
    const int*   ei  = (const int*)d_in[1];
    const float* W1  = (const float*)d_in[2];
    const float* as1 = (const float*)d_in[3];
    const float* ad1 = (const float*)d_in[4];
    const float* b1  = (const float*)d_in[5];
    const float* W2  = (const float*)d_in[6];
    const float* as2 = (const float*)d_in[7];
    const float* ad2 = (const float*)d_in[8];
    const float* b2  = (const float*)d_in[9];
    const float* Wf1 = (const float*)d_in[10];
    const float* bf1 = (const float*)d_in[11];
    const float* Wf2 = (const float*)d_in[12];
    const float* bf2 = (const float*)d_in[13];
    float* out = (float*)d_out;

    char* ws = (char*)d_ws;
    size_t off = 0;
    auto alloc = [&](size_t b) { size_t o = off; off += (b + 255) & ~(size_t)255; return o; };
    unsigned short* W1T = (unsigned short*)(ws + alloc((size_t)HC * IN_CH * 2));       // W1^T bf16
    unsigned short* W2T = (unsigned short*)(ws + alloc((size_t)HC * HC * 2));          // W2^T bf16
    unsigned short* HB  = (unsigned short*)(ws + alloc((size_t)N_NODES * HC * 2));     // h bf16
    unsigned short* ACT = (unsigned short*)(ws + alloc((size_t)N_NODES * HC * 2));     // act bf16
    int*   SRC  = (int*)  (ws + alloc((size_t)(EP + 64) * 4));
    unsigned int* STG = (unsigned int*)(ws + alloc((size_t)(EP + 64) * 4));            // bucket staging
    float* AS   = (float*)(ws + alloc((size_t)N_NODES * 3 * 4));
    float* AD   = (float*)(ws + alloc((size_t)N_NODES * 3 * 4));
    int*   OFFS = (int*)  (ws + alloc((size_t)(N_NODES + 4) * 4));
    int*   CNT  = (int*)  (ws + alloc((size_t)(N_NODES + 16 + 512) * 4)); // + MKEY + BCNT
    unsigned int* MKEY = (unsigned int*)(CNT + N_NODES);             // [0..2] L1, [3..5] L2
    int*   BCNT = CNT + N_NODES + 16;                                // NBKT bucket counters
    int*   BSUM = (int*)  (ws + alloc((size_t)256 * 4));
    unsigned short* WFT = (unsigned short*)(ws + alloc((size_t)OUT_CH * HC * 2));      // (Wf1@Wf2)^T bf16
    float* BF   = (float*)(ws + alloc((size_t)OUT_CH * 4));

    int gmb = (N_NODES + GBM - 1) / GBM;    // 391

    hipMemsetAsync(CNT, 0, (size_t)(N_NODES + 16 + 512) * 4, stream);  // CNT + MKEY + BCNT
    mega_pre_kernel<<<MB_HIST, 256, 0, stream>>>(W1, W1T, W2, W2T,
                                                 Wf1, bf1, Wf2, bf2, WFT, BF, ei, CNT);
    scan_local_kernel<<<SCAN_BLK, 256, 0, stream>>>(CNT, OFFS, BSUM);
    scan_add_kernel<<<SCAN_BLK, 256, 0, stream>>>(OFFS, BSUM);
    scatter1_kernel<<<NB1, 256, 0, stream>>>(ei, OFFS, BCNT, STG);
    scatter2_kernel<<<NBKT, 256, 0, stream>>>(STG, OFFS, SRC);

    // layer 1 (A = fp32 x, converted in staging)
    gemm_mfma_kernel<IN_CH, true><<<gmb, 256, 0, stream>>>(x, nullptr, W1T, as1, ad1, HB, AS, AD, MKEY);
    aggregate_kernel<<<N_NODES / 2, 256, 0, stream>>>(SRC, OFFS, AS, AD, MKEY, HB, b1, ACT);
    // layer 2 (A = bf16 ACT)
    gemm_mfma_kernel<HC, false><<<gmb, 256, 0, stream>>>(nullptr, ACT, W2T, as2, ad2, HB, AS, AD, MKEY + 3);
    aggregate_kernel<<<N_NODES / 2, 256, 0, stream>>>(SRC, OFFS, AS, AD, MKEY + 3, HB, b2, ACT);
    // head (MFMA)
    mlp_mfma_kernel<<<gmb, 256, 0, stream>>>(ACT, WFT, BF, out);
}

// Round 20
// 264.101 us; speedup vs baseline: 1.1024x; 1.1024x over previous
//
#include <hip/hip_runtime.h>

#define N_NODES 50000
#define E_EDGES 800000
#define EP (E_EDGES + N_NODES)   // edges + self loops = 850000
#define IN_CH 128
#define HID 64
#define HEADS 3
#define HC 192
#define OUT_CH 32
#define SLOPE 0.2f

#define N4 12500                 // N_NODES / 4 (exact)
#define SCAN_BLK 49              // ceil(N4 / 256)
#define NBKT 391                 // ceil(N_NODES / 128) dst buckets
#define SCAP 4096                // pass-2 LDS capacity (mean 2176, +41 sigma)
#define EPB 8192                 // edges per scatter1 block
#define NB1 104                  // ceil(EP / EPB)

// mega_pre job boundaries
#define MB_W1 96                 // 128k x 192n: 4 k-tiles x 24 n-tiles
#define MB_W2 (MB_W1 + 144)      // 192k x 192n: 6 k-tiles x 24 n-tiles
#define MB_FOLD (MB_W2 + 25)
#define MB_HIST (MB_FOLD + 3321) // ceil(EP/256)

typedef __attribute__((ext_vector_type(8))) short bf16x8;
typedef __attribute__((ext_vector_type(4))) float f32x4;

__device__ __forceinline__ unsigned short f2bf(float f) {
    unsigned int u = __float_as_uint(f);
    u = (u + 0x7fffu + ((u >> 16) & 1u)) >> 16;   // round-to-nearest-even
    return (unsigned short)u;
}
__device__ __forceinline__ float loF(unsigned int u) { return __uint_as_float(u << 16); }
__device__ __forceinline__ float hiF(unsigned int u) { return __uint_as_float(u & 0xFFFF0000u); }

// monotone float<->uint key (memset-0 init acts as -inf)
__device__ __forceinline__ unsigned int fkey(float f) {
    unsigned int u = __float_as_uint(f);
    return (u & 0x80000000u) ? ~u : (u | 0x80000000u);
}
__device__ __forceinline__ float unfkey(unsigned int k) {
    unsigned int u = (k & 0x80000000u) ? (k ^ 0x80000000u) : ~k;
    return __uint_as_float(u);
}

// ---------------- fused preprocessing: wconv1 | wconv2 | fold | hist ----------------

__global__ __launch_bounds__(256) void mega_pre_kernel(
    const float* __restrict__ W1, unsigned short* __restrict__ W1T,
    const float* __restrict__ W2, unsigned short* __restrict__ W2T,
    const float* __restrict__ Wf1, const float* __restrict__ bf1,
    const float* __restrict__ Wf2, const float* __restrict__ bf2,
    unsigned short* __restrict__ WfTb, float* __restrict__ bf,
    const int* __restrict__ ei, int* __restrict__ cnt) {
    int b = blockIdx.x, t = threadIdx.x;
    if (b < MB_W1) {                          // W1 [128][192] -> W1T [192][128] bf16
        int k = (b & 3) * 32 + (t & 31);
        int n = (b >> 2) * 8 + (t >> 5);
        W1T[n * IN_CH + k] = f2bf(W1[(size_t)k * HC + n]);
    } else if (b < MB_W2) {                   // W2 [192][192] -> W2T [192][192] bf16
        int bb = b - MB_W1;
        int k = (bb % 6) * 32 + (t & 31);
        int n = (bb / 6) * 8 + (t >> 5);
        W2T[n * HC + k] = f2bf(W2[(size_t)k * HC + n]);
    } else if (b < MB_FOLD) {                 // WfT = (Wf1@Wf2)^T bf16, bf = bf1@Wf2 + bf2
        int id = (b - MB_W2) * 256 + t;
        if (id < HC * OUT_CH) {
            int i = id / OUT_CH, j = id % OUT_CH;
            float s = 0.f;
            for (int k = 0; k < 64; ++k) s += Wf1[i * 64 + k] * Wf2[k * OUT_CH + j];
            WfTb[j * HC + i] = f2bf(s);
        } else if (id < HC * OUT_CH + OUT_CH) {
            int j = id - HC * OUT_CH;
            float s = bf2[j];
            for (int k = 0; k < 64; ++k) s += bf1[k] * Wf2[k * OUT_CH + j];
            bf[j] = s;
        }
    } else {                                  // degree histogram
        int i = (b - MB_FOLD) * 256 + t;
        if (i < EP) {
            int d = (i < E_EDGES) ? ei[E_EDGES + i] : (i - E_EDGES);
            atomicAdd(&cnt[d], 1);
        }
    }
}

// ---- hierarchical exclusive scan ----

__global__ __launch_bounds__(256) void scan_local_kernel(int* __restrict__ cnt,
                                                         int* __restrict__ offs,
                                                         int* __restrict__ bsum) {
    __shared__ int s[256];
    int t = threadIdx.x;
    int g = blockIdx.x * 256 + t;          // int4 index
    int4 v = make_int4(0, 0, 0, 0);
    if (g < N4) v = ((const int4*)cnt)[g];
    int sum = v.x + v.y + v.z + v.w;
    s[t] = sum; __syncthreads();
    #pragma unroll
    for (int o = 1; o < 256; o <<= 1) {
        int u = (t >= o) ? s[t - o] : 0;
        __syncthreads();
        s[t] += u;
        __syncthreads();
    }
    int ex = s[t] - sum;
    if (g < N4) {
        int4 w;
        w.x = ex;
        w.y = ex + v.x;
        w.z = ex + v.x + v.y;
        w.w = ex + v.x + v.y + v.z;
        ((int4*)offs)[g] = w;
    }
    if (t == 255) bsum[blockIdx.x] = s[255];
}

__global__ __launch_bounds__(256) void scan_add_kernel(int* __restrict__ offs,
                                                       const int* __restrict__ bsum) {
    int lane = threadIdx.x & 63;
    int orig = (lane < SCAN_BLK) ? bsum[lane] : 0;
    int v = orig;
    #pragma unroll
    for (int o = 1; o < 64; o <<= 1) {
        int u = __shfl_up(v, o);
        if (lane >= o) v += u;
    }
    // all lanes active for every shuffle (ds_bpermute from an inactive lane is UB)
    int add = __shfl(v, blockIdx.x) - __shfl(orig, blockIdx.x);   // exclusive prefix
    int total = __shfl(v, SCAN_BLK - 1);
    int g = blockIdx.x * 256 + threadIdx.x;
    if (g < N4) {
        int4 w = ((int4*)offs)[g];
        w.x += add; w.y += add; w.z += add; w.w += add;
        ((int4*)offs)[g] = w;
    }
    if (blockIdx.x == 0 && threadIdx.x == 0) offs[N_NODES] = total;
}

// ---- two-pass bucket sort with block-aggregated reservation ----

__global__ __launch_bounds__(256) void scatter1_kernel(const int* __restrict__ ei,
                                                       const int* __restrict__ offs,
                                                       int* __restrict__ bcnt,
                                                       unsigned int* __restrict__ stage) {
    __shared__ unsigned int pack[EPB];        // [bucket:9][lslot:13][dloc:7]
    __shared__ int hist[NBKT];
    __shared__ int basec[NBKT];
    int t = threadIdx.x;
    int e0 = blockIdx.x * EPB;
    int e1 = e0 + EPB; if (e1 > EP) e1 = EP;
    int n = e1 - e0;
    for (int b = t; b < NBKT; b += 256) hist[b] = 0;
    __syncthreads();
    for (int i = t; i < n; i += 256) {
        int gi = e0 + i;
        int d_ = (gi < E_EDGES) ? ei[E_EDGES + gi] : (gi - E_EDGES);
        int b = d_ >> 7;
        int lslot = atomicAdd(&hist[b], 1);
        pack[i] = ((unsigned int)b << 20) | ((unsigned int)lslot << 7) | (unsigned int)(d_ & 127);
    }
    __syncthreads();
    for (int b = t; b < NBKT; b += 256) {
        int h = hist[b];
        int res = (h > 0) ? atomicAdd(&bcnt[b], h) : 0;
        basec[b] = offs[b << 7] + res;
    }
    __syncthreads();
    for (int i = t; i < n; i += 256) {
        int gi = e0 + i;
        int s_ = (gi < E_EDGES) ? ei[gi] : (gi - E_EDGES);
        unsigned int pk = pack[i];
        int b = pk >> 20;
        int lslot = (pk >> 7) & 0x1FFF;
        unsigned int dloc = pk & 127u;
        stage[basec[b] + lslot] = (dloc << 16) | (unsigned int)s_;
    }
}

// Pass 2: per-bucket LDS counting sort; coalesced output.
__global__ __launch_bounds__(256) void scatter2_kernel(const unsigned int* __restrict__ stage,
                                                       const int* __restrict__ offs,
                                                       int* __restrict__ src_sort) {
    __shared__ unsigned int ents[SCAP];
    __shared__ int outb[SCAP];
    __shared__ int lcnt[128];
    __shared__ int lsc[128];
    int b = blockIdx.x, t = threadIdx.x;
    int beg = offs[b << 7];
    int hi = (b << 7) + 128; if (hi > N_NODES) hi = N_NODES;
    int end = offs[hi];
    int n = end - beg;
    if (t < 128) lcnt[t] = 0;
    __syncthreads();
    for (int i = t; i < n; i += 256) {
        unsigned int v = stage[beg + i];
        int dloc = (v >> 16) & 127;
        int slot = atomicAdd(&lcnt[dloc], 1);
        ents[i] = v | ((unsigned int)slot << 23);
    }
    __syncthreads();
    int cv = (t < 128) ? lcnt[t] : 0;
    if (t < 128) lsc[t] = cv;
    __syncthreads();
    #pragma unroll
    for (int o = 1; o < 128; o <<= 1) {
        int u = 0;
        if (t < 128 && t >= o) u = lsc[t - o];
        __syncthreads();
        if (t < 128) lsc[t] += u;
        __syncthreads();
    }
    if (t < 128) lsc[t] -= cv;                 // exclusive prefix
    __syncthreads();
    for (int i = t; i < n; i += 256) {
        unsigned int v = ents[i];
        int dloc = (v >> 16) & 127;
        int slot = v >> 23;
        outb[lsc[dloc] + slot] = (int)(v & 0xFFFFu);
    }
    __syncthreads();
    for (int i = t; i < n; i += 256) src_sort[beg + i] = outb[i];
}

// ---------------- MFMA GEMM: [M x K] @ [K x 192]bf16 -> Hb bf16 + alphas + global AS max ----------------

#define GBM 128
#define GBK 64
#define LDA 72        // row pad: 144 B, 16B-aligned, even bank spread
#define CS_STR 200    // epilogue C row stride (elems)

template <int K, bool XF32>
__global__ __launch_bounds__(256) void gemm_mfma_kernel(
    const float* __restrict__ Af, const unsigned short* __restrict__ Ab,
    const unsigned short* __restrict__ Wt,
    const float* __restrict__ a_src, const float* __restrict__ a_dst,
    unsigned short* __restrict__ Hb, float* __restrict__ AS, float* __restrict__ AD,
    unsigned int* __restrict__ mk) {
    __shared__ __align__(16) unsigned char smem[51200];
    __shared__ float pmx[4][3];
    unsigned short (*As)[LDA] = (unsigned short (*)[LDA])smem;
    unsigned short (*Bs)[LDA] = (unsigned short (*)[LDA])(smem + GBM * LDA * 2);
    int tid = threadIdx.x;
    int wid = tid >> 6, lane = tid & 63;
    int l15 = lane & 15, l4 = lane >> 4;
    int m0 = blockIdx.x * GBM;
    int sr = tid >> 3, sc = (tid & 7) * 8;

    f32x4 acc[2][12];
    #pragma unroll
    for (int m = 0; m < 2; ++m)
        #pragma unroll
        for (int n = 0; n < 12; ++n) acc[m][n] = (f32x4){0.f, 0.f, 0.f, 0.f};

    for (int kb = 0; kb < K; kb += GBK) {
        #pragma unroll
        for (int i = 0; i < 4; ++i) {           // A tile: 128 rows x 64 k
            int r = sr + 32 * i, grow = m0 + r;
            uint4 v = make_uint4(0, 0, 0, 0);
            if (XF32) {
                if (grow < N_NODES) {
                    const float* xp = Af + (size_t)grow * K + kb + sc;
                    float4 v0 = *(const float4*)xp;
                    float4 v1 = *(const float4*)(xp + 4);
                    v.x = (unsigned int)f2bf(v0.x) | ((unsigned int)f2bf(v0.y) << 16);
                    v.y = (unsigned int)f2bf(v0.z) | ((unsigned int)f2bf(v0.w) << 16);
                    v.z = (unsigned int)f2bf(v1.x) | ((unsigned int)f2bf(v1.y) << 16);
                    v.w = (unsigned int)f2bf(v1.z) | ((unsigned int)f2bf(v1.w) << 16);
                }
            } else {
                if (grow < N_NODES) v = *(const uint4*)&Ab[(size_t)grow * K + kb + sc];
            }
            *(uint4*)&As[r][sc] = v;
        }
        #pragma unroll
        for (int i = 0; i < 6; ++i) {           // B tile: 192 n x 64 k (k-contig)
            int n = sr + 32 * i;
            uint4 v = *(const uint4*)&Wt[(size_t)n * K + kb + sc];
            *(uint4*)&Bs[n][sc] = v;
        }
        __syncthreads();
        #pragma unroll
        for (int ks = 0; ks < 2; ++ks) {
            int ko = ks * 32 + l4 * 8;
            bf16x8 a0 = *(const bf16x8*)&As[wid * 32 + l15][ko];
            bf16x8 a1 = *(const bf16x8*)&As[wid * 32 + 16 + l15][ko];
            #pragma unroll
            for (int n = 0; n < 12; ++n) {
                bf16x8 b = *(const bf16x8*)&Bs[n * 16 + l15][ko];
                acc[0][n] = __builtin_amdgcn_mfma_f32_16x16x32_bf16(a0, b, acc[0][n], 0, 0, 0);
                acc[1][n] = __builtin_amdgcn_mfma_f32_16x16x32_bf16(a1, b, acc[1][n], 0, 0, 0);
            }
        }
        __syncthreads();
    }

    // ---- fused alpha + per-wave AS max ----
    float asv[12], adv[12];
    #pragma unroll
    for (int n = 0; n < 12; ++n) {
        asv[n] = a_src[n * 16 + l15];
        adv[n] = a_dst[n * 16 + l15];
    }
    float pm[3] = {-1e30f, -1e30f, -1e30f};
    #pragma unroll
    for (int m = 0; m < 2; ++m)
        #pragma unroll
        for (int r = 0; r < 4; ++r) {
            float ps[3], pd[3];
            #pragma unroll
            for (int h = 0; h < 3; ++h) {
                float s = 0.f, d = 0.f;
                #pragma unroll
                for (int j = 0; j < 4; ++j) {
                    float v = acc[m][4 * h + j][r];
                    s += v * asv[4 * h + j];
                    d += v * adv[4 * h + j];
                }
                #pragma unroll
                for (int o = 1; o < 16; o <<= 1) { s += __shfl_xor(s, o); d += __shfl_xor(d, o); }
                ps[h] = s; pd[h] = d;
                pm[h] = fmaxf(pm[h], s);
            }
            if (l15 == 0) {
                int grow = m0 + wid * 32 + m * 16 + l4 * 4 + r;
                if (grow < N_NODES) {
                    #pragma unroll
                    for (int h = 0; h < 3; ++h) {
                        AS[grow * 3 + h] = ps[h];
                        AD[grow * 3 + h] = pd[h];
                    }
                }
            }
        }
    // wave-level max (all lanes active for shuffles), then stage to LDS
    #pragma unroll
    for (int h = 0; h < 3; ++h) {
        pm[h] = fmaxf(pm[h], __shfl_xor(pm[h], 16));
        pm[h] = fmaxf(pm[h], __shfl_xor(pm[h], 32));
    }
    if (lane == 0) { pmx[wid][0] = pm[0]; pmx[wid][1] = pm[1]; pmx[wid][2] = pm[2]; }

    // ---- Hb store via per-wave LDS transpose (reuse tile space) ----
    unsigned short* Cw = (unsigned short*)smem + wid * 32 * CS_STR;
    #pragma unroll
    for (int m = 0; m < 2; ++m)
        #pragma unroll
        for (int n = 0; n < 12; ++n)
            #pragma unroll
            for (int r = 0; r < 4; ++r)
                Cw[(m * 16 + l4 * 4 + r) * CS_STR + n * 16 + l15] = f2bf(acc[m][n][r]);
    __syncthreads();
    #pragma unroll
    for (int i = 0; i < 12; ++i) {
        int c = lane + 64 * i;                 // 768 chunks of 16B per wave
        int row = c / 24, off = c % 24;
        int grow = m0 + wid * 32 + row;
        if (grow < N_NODES) {
            uint4 v = *(const uint4*)&Cw[row * CS_STR + off * 8];
            *(uint4*)&Hb[(size_t)grow * HC + off * 8] = v;
        }
    }
    // one atomicMax per block per head (contention: 391 blocks x 3 addrs - negligible)
    if (tid < 3) {
        float bm = fmaxf(fmaxf(pmx[0][tid], pmx[1][tid]), fmaxf(pmx[2][tid], pmx[3][tid]));
        atomicMax(&mk[tid], fkey(bm));
    }
}

// ---------------- single-pass softmax + gather-sum, one wave per dst (R12 layout) ----------------

__global__ __launch_bounds__(256) void aggregate_kernel(
    const int* __restrict__ src_sort, const int* __restrict__ offs,
    const float* __restrict__ AS, const float* __restrict__ AD,
    const unsigned int* __restrict__ mkey,
    const unsigned short* __restrict__ Hb, const float* __restrict__ bias,
    unsigned short* __restrict__ Aout) {
    int w = blockIdx.x * 4 + (threadIdx.x >> 6);
    int lane = threadIdx.x & 63;
    int g = lane >> 4, l = lane & 15;
    int beg = offs[w], end = offs[w + 1];

    float ad = 0.f, m = 0.f;
    if (l < 3) {
        ad = AD[w * 3 + l];
        float sm = unfkey(mkey[l]) + ad;
        m = fmaxf(sm, SLOPE * sm);             // lrelu(gmax+ad) >= max_e lrelu(AS+ad)
    }

    int c0 = l * 12;
    int h0 = c0 >> 6, h1 = (c0 + 4) >> 6, h2 = (c0 + 8) >> 6;
    float A0 = 0.f, A1 = 0.f, A2 = 0.f, A3 = 0.f;
    float B0 = 0.f, B1 = 0.f, B2 = 0.f, B3 = 0.f;
    float C0 = 0.f, C1 = 0.f, C2 = 0.f, C3 = 0.f;
    float den = 0.f;

    // prologue: edge 0..3 score chain
    int p = beg + g;
    bool pv = p < end;
    int s_ = src_sort[pv ? p : (end - 1)];     // deg >= 1 (self-loop)
    float e_;
    {
        float v = (l < 3) ? (AS[s_ * 3 + l] + ad) : 0.f;
        v = fmaxf(v, SLOPE * v);
        e_ = (pv && l < 3) ? __expf(v - m) : 0.f;
    }
    for (int p0 = beg; p0 < end; p0 += 4) {
        // issue next iteration's index load first
        int pn = p0 + 4 + g;
        bool pnv = pn < end;
        int sn = src_sort[pnv ? pn : (end - 1)];
        // current row gathers (latency hidden under next-score computation)
        const unsigned short* hr = Hb + (unsigned)s_ * HC + c0;
        uint2 v0 = *(const uint2*)hr;
        uint2 v1 = *(const uint2*)(hr + 4);
        uint2 v2 = *(const uint2*)(hr + 8);
        // next iteration's score (independent of gathers)
        float en;
        {
            float v = (l < 3) ? (AS[sn * 3 + l] + ad) : 0.f;
            v = fmaxf(v, SLOPE * v);
            en = (pnv && l < 3) ? __expf(v - m) : 0.f;
        }
        // accumulate with current weight
        den += e_;
        float w0 = __shfl(e_, g * 16 + h0);
        float w1 = __shfl(e_, g * 16 + h1);
        float w2 = __shfl(e_, g * 16 + h2);
        A0 += w0 * loF(v0.x); A1 += w0 * hiF(v0.x); A2 += w0 * loF(v0.y); A3 += w0 * hiF(v0.y);
        B0 += w1 * loF(v1.x); B1 += w1 * hiF(v1.x); B2 += w1 * loF(v1.y); B3 += w1 * hiF(v1.y);
        C0 += w2 * loF(v2.x); C1 += w2 * hiF(v2.x); C2 += w2 * loF(v2.y); C3 += w2 * hiF(v2.y);
        s_ = sn; e_ = en;
    }

    // cross-slot reduction
    #pragma unroll
    for (int o = 16; o < 64; o <<= 1) {
        A0 += __shfl_xor(A0, o); A1 += __shfl_xor(A1, o); A2 += __shfl_xor(A2, o); A3 += __shfl_xor(A3, o);
        B0 += __shfl_xor(B0, o); B1 += __shfl_xor(B1, o); B2 += __shfl_xor(B2, o); B3 += __shfl_xor(B3, o);
        C0 += __shfl_xor(C0, o); C1 += __shfl_xor(C1, o); C2 += __shfl_xor(C2, o); C3 += __shfl_xor(C3, o);
        den += __shfl_xor(den, o);
    }
    float i0 = 1.f / (__shfl(den, h0) + 1e-16f);
    float i1 = 1.f / (__shfl(den, h1) + 1e-16f);
    float i2 = 1.f / (__shfl(den, h2) + 1e-16f);

    if (lane < 16) {
        float4 bi0 = *(const float4*)&bias[c0];
        float4 bi1 = *(const float4*)&bias[c0 + 4];
        float4 bi2 = *(const float4*)&bias[c0 + 8];
        A0 = A0 * i0 + bi0.x; A1 = A1 * i0 + bi0.y; A2 = A2 * i0 + bi0.z; A3 = A3 * i0 + bi0.w;
        B0 = B0 * i1 + bi1.x; B1 = B1 * i1 + bi1.y; B2 = B2 * i1 + bi1.z; B3 = B3 * i1 + bi1.w;
        C0 = C0 * i2 + bi2.x; C1 = C1 * i2 + bi2.y; C2 = C2 * i2 + bi2.z; C3 = C3 * i2 + bi2.w;
        A0 = (A0 > 0.f) ? A0 : (__expf(A0) - 1.f);
        A1 = (A1 > 0.f) ? A1 : (__expf(A1) - 1.f);
        A2 = (A2 > 0.f) ? A2 : (__expf(A2) - 1.f);
        A3 = (A3 > 0.f) ? A3 : (__expf(A3) - 1.f);
        B0 = (B0 > 0.f) ? B0 : (__expf(B0) - 1.f);
        B1 = (B1 > 0.f) ? B1 : (__expf(B1) - 1.f);
        B2 = (B2 > 0.f) ? B2 : (__expf(B2) - 1.f);
        B3 = (B3 > 0.f) ? B3 : (__expf(B3) - 1.f);
        C0 = (C0 > 0.f) ? C0 : (__expf(C0) - 1.f);
        C1 = (C1 > 0.f) ? C1 : (__expf(C1) - 1.f);
        C2 = (C2 > 0.f) ? C2 : (__expf(C2) - 1.f);
        C3 = (C3 > 0.f) ? C3 : (__expf(C3) - 1.f);
        unsigned short* op = Aout + (size_t)w * HC + c0;
        uint2 o0, o1, o2;
        o0.x = (unsigned int)f2bf(A0) | ((unsigned int)f2bf(A1) << 16);
        o0.y = (unsigned int)f2bf(A2) | ((unsigned int)f2bf(A3) << 16);
        o1.x = (unsigned int)f2bf(B0) | ((unsigned int)f2bf(B1) << 16);
        o1.y = (unsigned int)f2bf(B2) | ((unsigned int)f2bf(B3) << 16);
        o2.x = (unsigned int)f2bf(C0) | ((unsigned int)f2bf(C1) << 16);
        o2.y = (unsigned int)f2bf(C2) | ((unsigned int)f2bf(C3) << 16);
        *(uint2*)op = o0;
        *(uint2*)(op + 4) = o1;
        *(uint2*)(op + 8) = o2;
    }
}

// ---------------- MFMA MLP head: out = act(bf16) @ WfT^T + bf ----------------

__global__ __launch_bounds__(256) void mlp_mfma_kernel(
    const unsigned short* __restrict__ act, const unsigned short* __restrict__ WfTb,
    const float* __restrict__ bf, float* __restrict__ out) {
    int tid = threadIdx.x;
    int wid = tid >> 6, lane = tid & 63;
    int l15 = lane & 15, l4 = lane >> 4;
    int m0 = blockIdx.x * 128 + wid * 32;

    f32x4 acc[2][2];
    #pragma unroll
    for (int m = 0; m < 2; ++m)
        #pragma unroll
        for (int n = 0; n < 2; ++n) acc[m][n] = (f32x4){0.f, 0.f, 0.f, 0.f};

    int r0 = m0 + l15, r1 = m0 + 16 + l15;
    bool v0r = r0 < N_NODES, v1r = r1 < N_NODES;
    const unsigned short* a0p = act + (size_t)(v0r ? r0 : 0) * HC;
    const unsigned short* a1p = act + (size_t)(v1r ? r1 : 0) * HC;
    const unsigned short* b0p = WfTb + (size_t)l15 * HC;
    const unsigned short* b1p = WfTb + (size_t)(16 + l15) * HC;

    #pragma unroll
    for (int ks = 0; ks < 6; ++ks) {
        int k0 = ks * 32 + l4 * 8;
        bf16x8 a0 = *(const bf16x8*)&a0p[k0];
        bf16x8 a1 = *(const bf16x8*)&a1p[k0];
        bf16x8 b0 = *(const bf16x8*)&b0p[k0];
        bf16x8 b1 = *(const bf16x8*)&b1p[k0];
        acc[0][0] = __builtin_amdgcn_mfma_f32_16x16x32_bf16(a0, b0, acc[0][0], 0, 0, 0);
        acc[0][1] = __builtin_amdgcn_mfma_f32_16x16x32_bf16(a0, b1, acc[0][1], 0, 0, 0);
        acc[1][0] = __builtin_amdgcn_mfma_f32_16x16x32_bf16(a1, b0, acc[1][0], 0, 0, 0);
        acc[1][1] = __builtin_amdgcn_mfma_f32_16x16x32_bf16(a1, b1, acc[1][1], 0, 0, 0);
    }

    float bv0 = bf[l15], bv1 = bf[16 + l15];
    #pragma unroll
    for (int m = 0; m < 2; ++m)
        #pragma unroll
        for (int r = 0; r < 4; ++r) {
            int row = m0 + m * 16 + l4 * 4 + r;
            if (row < N_NODES) {
                out[(size_t)row * OUT_CH + l15]      = acc[m][0][r] + bv0;
                out[(size_t)row * OUT_CH + 16 + l15] = acc[m][1][r] + bv1;
            }
        }
}

// ---------------- launch ----------------

extern "C" void kernel_launch(void* const* d_in, const int* in_sizes, int n_in,
                              void* d_out, int out_size, void* d_ws, size_t ws_size,
                              hipStream_t stream) {
    (void)in_sizes; (void)n_in; (void)out_size; (void)ws_size;
    const float* x   = (const float*)d_in[0];
    const int*   ei  = (const int*)d_in[1];
    const float* W1  = (const float*)d_in[2];
    const float* as1 = (const float*)d_in[3];
    const float* ad1 = (const float*)d_in[4];
    const float* b1  = (const float*)d_in[5];
    const float* W2  = (const float*)d_in[6];
    const float* as2 = (const float*)d_in[7];
    const float* ad2 = (const float*)d_in[8];
    const float* b2  = (const float*)d_in[9];
    const float* Wf1 = (const float*)d_in[10];
    const float* bf1 = (const float*)d_in[11];
    const float* Wf2 = (const float*)d_in[12];
    const float* bf2 = (const float*)d_in[13];
    float* out = (float*)d_out;

    char* ws = (char*)d_ws;
    size_t off = 0;
    auto alloc = [&](size_t b) { size_t o = off; off += (b + 255) & ~(size_t)255; return o; };
    unsigned short* W1T = (unsigned short*)(ws + alloc((size_t)HC * IN_CH * 2));       // W1^T bf16
    unsigned short* W2T = (unsigned short*)(ws + alloc((size_t)HC * HC * 2));          // W2^T bf16
    unsigned short* HB  = (unsigned short*)(ws + alloc((size_t)N_NODES * HC * 2));     // h bf16
    unsigned short* ACT = (unsigned short*)(ws + alloc((size_t)N_NODES * HC * 2));     // act bf16
    int*   SRC  = (int*)  (ws + alloc((size_t)(EP + 64) * 4));
    unsigned int* STG = (unsigned int*)(ws + alloc((size_t)(EP + 64) * 4));            // bucket staging
    float* AS   = (float*)(ws + alloc((size_t)N_NODES * 3 * 4));
    float* AD   = (float*)(ws + alloc((size_t)N_NODES * 3 * 4));
    int*   OFFS = (int*)  (ws + alloc((size_t)(N_NODES + 4) * 4));
    int*   CNT  = (int*)  (ws + alloc((size_t)(N_NODES + 16 + 512) * 4)); // + MKEY + BCNT
    unsigned int* MKEY = (unsigned int*)(CNT + N_NODES);             // [0..2] L1, [3..5] L2
    int*   BCNT = CNT + N_NODES + 16;                                // NBKT bucket counters
    int*   BSUM = (int*)  (ws + alloc((size_t)256 * 4));
    unsigned short* WFT = (unsigned short*)(ws + alloc((size_t)OUT_CH * HC * 2));      // (Wf1@Wf2)^T bf16
    float* BF   = (float*)(ws + alloc((size_t)OUT_CH * 4));

    int gmb = (N_NODES + GBM - 1) / GBM;    // 391

    hipMemsetAsync(CNT, 0, (size_t)(N_NODES + 16 + 512) * 4, stream);  // CNT + MKEY + BCNT
    mega_pre_kernel<<<MB_HIST, 256, 0, stream>>>(W1, W1T, W2, W2T,
                                                 Wf1, bf1, Wf2, bf2, WFT, BF, ei, CNT);
    scan_local_kernel<<<SCAN_BLK, 256, 0, stream>>>(CNT, OFFS, BSUM);
    scan_add_kernel<<<SCAN_BLK, 256, 0, stream>>>(OFFS, BSUM);
    scatter1_kernel<<<NB1, 256, 0, stream>>>(ei, OFFS, BCNT, STG);
    scatter2_kernel<<<NBKT, 256, 0, stream>>>(STG, OFFS, SRC);

    // layer 1 (A = fp32 x, converted in staging)
    gemm_mfma_kernel<IN_CH, true><<<gmb, 256, 0, stream>>>(x, nullptr, W1T, as1, ad1, HB, AS, AD, MKEY);
    aggregate_kernel<<<(N_NODES + 3) / 4, 256, 0, stream>>>(SRC, OFFS, AS, AD, MKEY, HB, b1, ACT);
    // layer 2 (A = bf16 ACT)
    gemm_mfma_kernel<HC, false><<<gmb, 256, 0, stream>>>(nullptr, ACT, W2T, as2, ad2, HB, AS, AD, MKEY + 3);
    aggregate_kernel<<<(N_NODES + 3) / 4, 256, 0, stream>>>(SRC, OFFS, AS, AD, MKEY + 3, HB, b2, ACT);
    // head (MFMA)
    mlp_mfma_kernel<<<gmb, 256, 0, stream>>>(ACT, WFT, BF, out);
}